// Round 6
// baseline (262.443 us; speedup 1.0000x reference)
//
#include <hip/hip_runtime.h>

static constexpr int B = 256, L = 2048, T = 17;
#define LOG2E 1.4426950408889634f
#define LN2   0.6931471805599453f

// broadcast lane i's float to all lanes via v_readlane (SGPR result)
__device__ __forceinline__ float rl(float v, int i) {
  return __int_as_float(__builtin_amdgcn_readlane(__float_as_int(v), i));
}

// ---------------------------------------------------------------------------
// Fused CRF kernel. One block per batch, 4 waves:
//   wave 0   : forward scan in LINEAR domain (denominator)
//   waves 1-3: gold-path numerator (runs concurrently on other SIMDs)
// Linear-domain scan: N'_j = (sum_i N_i * W_ij) * Em_j.
// __launch_bounds__(256, 1): we run 1 block/CU (latency-bound serial chain);
// do NOT let the occupancy heuristic cap VGPRs (R4: VGPR_Count=24 forced
// w[]/emr[] into AGPR shuttling on the critical path, ~221 cyc/step).
// ---------------------------------------------------------------------------
__global__ __launch_bounds__(256, 1) void crf_fused_kernel(
    const float* __restrict__ em, const int* __restrict__ tags,
    const int* __restrict__ mask, const float* __restrict__ startT,
    const float* __restrict__ endT, const float* __restrict__ trans,
    float* __restrict__ out)
{
  const int tid = threadIdx.x;
  const int b = blockIdx.x;

  __shared__ float s_den;
  __shared__ float red[256];
  __shared__ int   redc[256];

  const float* emb = em + (size_t)b * L * T;
  const int*   mkb = mask + (size_t)b * L;
  const int*   tg  = tags + (size_t)b * L;

  if (tid < 64) {
    // ------------------------- scan wave -------------------------
    const int lane = tid;
    const int jj = (lane < T) ? lane : (T - 1);   // idle lanes mirror state 16

    float w[T];
#pragma unroll
    for (int i = 0; i < T; ++i) w[i] = exp2f(trans[i * T + jj] * LOG2E);

    // init (t=0): alpha'_j = (start_j + em0_j)*log2e, renorm to lane 0
    float v0 = (startT[jj] + emb[jj]) * LOG2E;
    float C = rl(v0, 0);
    float N = exp2f(v0 - C);

    // one scan step: N = m ? (W^T N) * Em : N
    // All 17 readlanes issued up front so their latency overlaps.
    auto step = [&](float Em, int mt) {
      const float n0  = rl(N, 0),  n1  = rl(N, 1),  n2  = rl(N, 2);
      const float n3  = rl(N, 3),  n4  = rl(N, 4),  n5  = rl(N, 5);
      const float n6  = rl(N, 6),  n7  = rl(N, 7),  n8  = rl(N, 8);
      const float n9  = rl(N, 9),  n10 = rl(N, 10), n11 = rl(N, 11);
      const float n12 = rl(N, 12), n13 = rl(N, 13), n14 = rl(N, 14);
      const float n15 = rl(N, 15), n16 = rl(N, 16);
      float s0 = n0 * w[0];
      float s1 = n1 * w[1];
      float s2 = n2 * w[2];
      float s3 = n3 * w[3];
      s0 = fmaf(n4,  w[4],  s0);
      s1 = fmaf(n5,  w[5],  s1);
      s2 = fmaf(n6,  w[6],  s2);
      s3 = fmaf(n7,  w[7],  s3);
      s0 = fmaf(n8,  w[8],  s0);
      s1 = fmaf(n9,  w[9],  s1);
      s2 = fmaf(n10, w[10], s2);
      s3 = fmaf(n11, w[11], s3);
      s0 = fmaf(n12, w[12], s0);
      s1 = fmaf(n13, w[13], s1);
      s2 = fmaf(n14, w[14], s2);
      s3 = fmaf(n15, w[15], s3);
      s0 = fmaf(n16, w[16], s0);
      const float S = (s0 + s1) + (s2 + s3);
      const float Nn = S * Em;
      N = mt ? Nn : N;
    };

    // exact power-of-2 renormalization (keeps lane0 ~ [1,2))
    auto renorm = [&]() {
      const int bits = __builtin_amdgcn_readlane(__float_as_int(N), 0);
      const int Ee = (bits >> 23) & 0xff;
      N *= __int_as_float((254 - Ee) << 23);
      C += (float)(Ee - 127);
    };

    // prologue: steps t = 1..7 (unpipelined)
    for (int t = 1; t < 8; ++t) {
      const float e = emb[(size_t)t * T + jj];
      const int   m = mkb[t];
      step(exp2f(e * LOG2E), m);
    }
    renorm();

    // preload first 8-step block (t = 8..15)
    float emr[8];
#pragma unroll
    for (int k = 0; k < 8; ++k) emr[k] = emb[(size_t)(8 + k) * T + jj];
    int4 mA = *(const int4*)(mkb + 8);
    int4 mB = *(const int4*)(mkb + 12);

    // main loop: 255 blocks of 8 steps (t = 8..2047)
    for (int blk = 0; blk < 255; ++blk) {
      const int t0 = 8 + blk * 8;

      float Emc[8];
#pragma unroll
      for (int k = 0; k < 8; ++k) Emc[k] = exp2f(emr[k] * LOG2E);
      const int cm[8] = {mA.x, mA.y, mA.z, mA.w, mB.x, mB.y, mB.z, mB.w};

      if (blk < 254) {   // prefetch next block (has ~8 steps to land)
#pragma unroll
        for (int k = 0; k < 8; ++k)
          emr[k] = emb[(size_t)(t0 + 8 + k) * T + jj];
        mA = *(const int4*)(mkb + t0 + 8);
        mB = *(const int4*)(mkb + t0 + 12);
      }

#pragma unroll
      for (int k = 0; k < 8; ++k) step(Emc[k], cm[k]);
      renorm();
    }

    // denominator = ln2 * (C + log2 sum_j N_j * 2^(end'_j))
    const float E2 = N * exp2f(endT[jj] * LOG2E);
    float ssum = 0.f;
#pragma unroll
    for (int i = 0; i < T; ++i) ssum += rl(E2, i);
    const float den = (C + log2f(ssum)) * LN2;
    if (lane == 0) s_den = den;

  } else {
    // ---------------------- numerator waves ----------------------
    float s = 0.f; int cnt = 0;
    for (int t = tid - 64; t < L; t += 192) {
      const int tag = tg[t];
      const int m   = mkb[t];
      cnt += (m != 0) ? 1 : 0;
      if (t == 0) {
        s += startT[tag] + emb[tag];
      } else if (m != 0) {
        s += trans[tg[t - 1] * T + tag] + emb[(size_t)t * T + tag];
      }
    }
    red[tid] = s; redc[tid] = cnt;
  }

  __syncthreads();
  if (tid == 0) {
    float ns = 0.f; int cnt = 0;
    for (int i = 64; i < 256; ++i) { ns += red[i]; cnt += redc[i]; }
    const int   last = tg[cnt - 1];
    const float num  = ns + endT[last];
    atomicAdd(out, (s_den - num) * (1.0f / B));
  }
}

// ---------------------------------------------------------------------------
extern "C" void kernel_launch(void* const* d_in, const int* in_sizes, int n_in,
                              void* d_out, int out_size, void* d_ws, size_t ws_size,
                              hipStream_t stream)
{
  const float* em   = (const float*)d_in[0];
  const int*   tags = (const int*)d_in[1];
  const int*   mask = (const int*)d_in[2];
  const float* st   = (const float*)d_in[3];
  const float* en   = (const float*)d_in[4];
  const float* tr   = (const float*)d_in[5];
  float* out = (float*)d_out;

  hipMemsetAsync(out, 0, sizeof(float), stream);   // harness poisons d_out
  crf_fused_kernel<<<B, 256, 0, stream>>>(em, tags, mask, st, en, tr, out);
}